// Round 3
// baseline (7182.989 us; speedup 1.0000x reference)
//
#include <hip/hip_runtime.h>

typedef unsigned int uint;
typedef unsigned short ushort;

#define B_  2
#define NA  2048
#define NN  48
#define G_  50
#define F_  128
#define NK  49   // Nn + 1 (self)

__device__ __forceinline__ float ssp(float z) {  // softplus(z) - ln2, stable
  return fmaxf(z, 0.f) + log1pf(__expf(-fabsf(z))) - 0.69314718055994531f;
}

struct __align__(16) Smem {
  float buf[6272];     // phase A: (2*f_ij-1) as [48][52]; phase B: y_full [49][128]
  float WF[48 * 128];  // P1: h1 (f32); after P2 in-place swap: W (f32, post-cutoff)
  float q[128];        // q, later reused as m
  float qk[128];       // Wk @ q
  float attn[64];
  float red[256];
  float C[48];         // cosine cutoff
  int   nbr[48];
};  // 52352 B -> 3 blocks/CU

extern "C" __global__ __launch_bounds__(256, 3)
void mpnn_kernel(const float* __restrict__ x, const float* __restrict__ r_ij,
                 const int* __restrict__ nbr, const int* __restrict__ pmask,
                 const float* __restrict__ fij,
                 const float* __restrict__ Wf1, const float* __restrict__ bf1,
                 const float* __restrict__ Wf2, const float* __restrict__ bf2p,
                 const float* __restrict__ Wq, const float* __restrict__ Wk,
                 const float* __restrict__ Wv, const float* __restrict__ Wo,
                 const float* __restrict__ bo,
                 float* __restrict__ out_m, float* __restrict__ out_W)
{
  __shared__ Smem sm;
  const int t = threadIdx.x;
  const int f = t & 127, h = t >> 7;     // feature lane, half
  const int lane = t & 63, w = t >> 6;   // wave-local
  const int a = blockIdx.x;              // atom id in [0, B*NA)
  const int b = a >> 11, i = a & 2047;
  const size_t base_nn = (size_t)a * NN;
  const size_t base_fg = (size_t)a * NN * G_;

  // ---- P0: stage (2*f_ij - 1), cutoff C(r), neighbor ids ----
  for (int jj = t; jj < NN * G_; jj += 256) {
    int n = jj / G_; int g = jj - n * G_;
    sm.buf[n * 52 + g] = 2.f * fij[base_fg + jj] - 1.f;
  }
  if (t < NN) {
    float r = r_ij[base_nn + t];
    sm.C[t] = (r < 5.0f) ? 0.5f * (cosf(0.62831853071795864769f * r) + 1.0f) : 0.0f;
    sm.nbr[t] = nbr[base_nn + t];
  }
  __syncthreads();

  // ---- P1: h1 = ssp( (2f-1) @ Wf1 + bf1 )  [48 x 50] @ [50 x 128] ----
  {
    float acc[24];
    float bb = bf1[f];
    #pragma unroll
    for (int j = 0; j < 24; ++j) acc[j] = bb;
    #pragma unroll
    for (int gc = 0; gc < 2; ++gc) {
      float wr[24];
      #pragma unroll
      for (int kk = 0; kk < 24; ++kk) wr[kk] = Wf1[(size_t)(gc * 24 + kk) * F_ + f];
      #pragma unroll
      for (int j = 0; j < 24; ++j) {
        const float* fr = &sm.buf[(h * 24 + j) * 52 + gc * 24];
        #pragma unroll
        for (int kk = 0; kk < 24; ++kk) acc[j] += fr[kk] * wr[kk];
      }
    }
    {
      float w0 = Wf1[(size_t)48 * F_ + f];
      float w1 = Wf1[(size_t)49 * F_ + f];
      #pragma unroll
      for (int j = 0; j < 24; ++j) {
        const float* fr = &sm.buf[(h * 24 + j) * 52];
        acc[j] += fr[48] * w0 + fr[49] * w1;
      }
    }
    #pragma unroll
    for (int j = 0; j < 24; ++j) sm.WF[(h * 24 + j) * F_ + f] = ssp(acc[j]);
  }
  __syncthreads();

  // ---- P2: W = (h1 @ Wf2 + bf2) * C, swapped IN-PLACE into WF (f32) ----
  {
    float acc[24];
    #pragma unroll
    for (int j = 0; j < 24; ++j) acc[j] = 0.f;
    #pragma unroll
    for (int kc = 0; kc < 4; ++kc) {
      float wr[32];
      #pragma unroll
      for (int kk = 0; kk < 32; ++kk) wr[kk] = Wf2[(size_t)(kc * 32 + kk) * F_ + f];
      #pragma unroll
      for (int j = 0; j < 24; ++j) {
        const float* hr = &sm.WF[(h * 24 + j) * F_ + kc * 32];
        #pragma unroll
        for (int kk = 0; kk < 32; ++kk) acc[j] += hr[kk] * wr[kk];
      }
    }
    __syncthreads();   // all h1 reads done before overwriting WF with W
    float b2 = bf2p[f];
    #pragma unroll
    for (int j = 0; j < 24; ++j) {
      int n = h * 24 + j;
      float wv = (acc[j] + b2) * sm.C[n];
      sm.WF[n * F_ + f] = wv;
      out_W[((size_t)a * NN + n) * F_ + f] = wv;
    }
  }
  __syncthreads();

  // ---- P3: gather y_full = [self, x[neighbors]] into buf [49][128] ----
  for (int row = w; row < NK; row += 4) {
    int src = (row == 0) ? i : sm.nbr[row - 1];
    const float2* xr = (const float2*)(x + ((size_t)b * NA + src) * F_);
    *(float2*)&sm.buf[row * F_ + lane * 2] = xr[lane];
  }
  __syncthreads();

  // ---- P4: q = x_self @ Wq ----
  {
    float p = 0.f;
    #pragma unroll 8
    for (int c = h * 64; c < h * 64 + 64; ++c)
      p += sm.buf[c] * Wq[(size_t)c * F_ + f];
    sm.red[h * F_ + f] = p;
  }
  __syncthreads();
  if (t < F_) sm.q[t] = sm.red[t] + sm.red[F_ + t];
  __syncthreads();

  // ---- P5: qk = Wk @ q  (row-dot via wave shuffle; kills the k-GEMM) ----
  for (int fo = w; fo < F_; fo += 4) {
    float2 ww = *(const float2*)(Wk + (size_t)fo * F_ + lane * 2);
    float p = ww.x * sm.q[lane * 2] + ww.y * sm.q[lane * 2 + 1];
    #pragma unroll
    for (int o = 32; o; o >>= 1) p += __shfl_xor(p, o);
    if (lane == 0) sm.qk[fo] = p;
  }
  __syncthreads();

  // ---- P6: scores + masked softmax ----
  {
    int n = lane;
    float p = 0.f;
    if (n < NK) {
      const float* yr = &sm.buf[n * F_ + w * 32];
      const float* qr = &sm.qk[w * 32];
      #pragma unroll
      for (int k = 0; k < 32; ++k) {
        int c = (k + n) & 31;   // lane-rotated: bank-conflict-free
        p += yr[c] * qr[c];
      }
    }
    sm.red[w * 64 + n] = p;
  }
  __syncthreads();
  if (t < 64) {
    float s = -1e30f;
    if (t < NK) {
      s = (sm.red[t] + sm.red[64 + t] + sm.red[128 + t] + sm.red[192 + t])
          * 0.08838834764831845f;   // 1/sqrt(128)
      if (t >= 1 && pmask[base_nn + t - 1] == 0) s = -1e9f;
    }
    float mx = s;
    #pragma unroll
    for (int o = 32; o; o >>= 1) mx = fmaxf(mx, __shfl_xor(mx, o));
    float ev = (t < NK) ? __expf(s - mx) : 0.f;
    float sum = ev;
    #pragma unroll
    for (int o = 32; o; o >>= 1) sum += __shfl_xor(sum, o);
    if (t < NK) sm.attn[t] = ev / sum;
  }
  __syncthreads();

  // ---- P7: m = sum_n attn[n] * mod[n] * (y_n @ Wv), v fused (never stored) ----
  {
    const int n0 = h ? 25 : 0;
    const int cnt = h ? 24 : 25;
    float vn[25];
    #pragma unroll
    for (int j = 0; j < 25; ++j) vn[j] = 0.f;
    #pragma unroll
    for (int kc = 0; kc < 4; ++kc) {
      float wr[32];
      #pragma unroll
      for (int kk = 0; kk < 32; ++kk) wr[kk] = Wv[(size_t)(kc * 32 + kk) * F_ + f];
      #pragma unroll
      for (int j = 0; j < 25; ++j) {
        if (j < cnt) {
          const float* yr = &sm.buf[(n0 + j) * F_ + kc * 32];
          #pragma unroll
          for (int kk = 0; kk < 32; ++kk) vn[j] += yr[kk] * wr[kk];
        }
      }
    }
    float msum = 0.f;
    #pragma unroll
    for (int j = 0; j < 25; ++j) {
      if (j < cnt) {
        int n = n0 + j;
        float coef = sm.attn[n];
        if (n > 0) coef *= sm.WF[(n - 1) * F_ + f];
        msum += coef * vn[j];
      }
    }
    sm.red[h * F_ + f] = msum;
  }
  __syncthreads();
  if (t < F_) sm.q[t] = sm.red[t] + sm.red[F_ + t];   // reuse q[] as m[]
  __syncthreads();

  // ---- P9: out_m = ssp(m @ Wo + bo) ----
  {
    float p = 0.f;
    #pragma unroll 8
    for (int c = h * 64; c < h * 64 + 64; ++c)
      p += sm.q[c] * Wo[(size_t)c * F_ + f];
    sm.red[h * F_ + f] = p;
  }
  __syncthreads();
  if (t < F_) {
    float v = sm.red[t] + sm.red[F_ + t] + bo[t];
    out_m[(size_t)a * F_ + t] = ssp(v);
  }
}

extern "C" void kernel_launch(void* const* d_in, const int* in_sizes, int n_in,
                              void* d_out, int out_size, void* d_ws, size_t ws_size,
                              hipStream_t stream) {
  // inputs: 0=e(unused) 1=x 2=t(unused) 3=r_ij 4=neighbors 5=pairwise_mask 6=f_ij
  //         7=Wf1 8=bf1 9=Wf2 10=bf2 11=Wq 12=Wk 13=Wv 14=Wo 15=bo
  const float* x   = (const float*)d_in[1];
  const float* r   = (const float*)d_in[3];
  const int*  nbr  = (const int*)d_in[4];
  const int*  pmk  = (const int*)d_in[5];
  const float* fij = (const float*)d_in[6];
  const float* Wf1 = (const float*)d_in[7];
  const float* bf1 = (const float*)d_in[8];
  const float* Wf2 = (const float*)d_in[9];
  const float* bf2p= (const float*)d_in[10];
  const float* Wq  = (const float*)d_in[11];
  const float* Wk  = (const float*)d_in[12];
  const float* Wv  = (const float*)d_in[13];
  const float* Wo  = (const float*)d_in[14];
  const float* bo  = (const float*)d_in[15];
  float* out_m = (float*)d_out;                       // [B,Na,F]
  float* out_W = out_m + (size_t)B_ * NA * F_;        // [B,Na,Nn,F]

  hipLaunchKernelGGL(mpnn_kernel, dim3(B_ * NA), dim3(256), 0, stream,
                     x, r, nbr, pmk, fij, Wf1, bf1, Wf2, bf2p,
                     Wq, Wk, Wv, Wo, bo, out_m, out_W);
}